// Round 16
// baseline (175.497 us; speedup 1.0000x reference)
//
#include <hip/hip_runtime.h>

#define FIN 128
#define FHID 16
#define NC 391           // coarse buckets (256 nodes each)
#define CSH 8
#define CAPC 9728        // per-bucket capacity (mean 8184; %4==0; mean+17sigma)
#define PCHUNK 6144      // R14-proven (R15's 3072 regressed: per-block fixed
#define PT 512           //  costs doubled, write coalescing worsened)
#define EPT 12           // PCHUNK/PT
#define NB_P 521         // partition blocks
#define FXB (1 << 20)    // per-term bias: term_fx = (int)(w*di*2^16) + FXB >= 0
#define IS16 (1.0f / 65536.0f)

typedef __attribute__((ext_vector_type(8))) short bf16x8;
typedef __attribute__((ext_vector_type(4))) float f32x4;

__device__ __forceinline__ unsigned bf16rne(float f) {
    unsigned u = __float_as_uint(f);
    return (u + 0x7FFFu + ((u >> 16) & 1u)) >> 16;
}

// block-wide inclusive scan via wave shfl; wsum = LDS[8]; 2 barriers.
__device__ __forceinline__ int block_scan_inc(int v, int* wsum, int tid, int nw) {
#pragma unroll
    for (int off = 1; off < 64; off <<= 1) {
        int t = __shfl_up(v, off, 64);
        if ((tid & 63) >= off) v += t;
    }
    int wid = tid >> 6;
    if ((tid & 63) == 63) wsum[wid] = v;
    __syncthreads();
    if (tid < nw) {
        int s = wsum[tid];
#pragma unroll
        for (int off = 1; off < 8; off <<= 1) {
            int t = __shfl_up(s, off, 64);
            if (tid >= off) s += t;
        }
        wsum[tid] = s;
    }
    __syncthreads();
    if (wid > 0) v += wsum[wid - 1];
    return v;
}

// ---------------- kernels ----------------

__global__ void k_init(int* __restrict__ cursorC, unsigned* __restrict__ hnb, int N) {
    int b = threadIdx.x;
    if (b < NC) cursorC[b] = b * CAPC;
    if (b == 0) {                          // zero sentinel row N of hnb
        ((uint4*)(hnb + (size_t)N * 8))[0] = make_uint4(0, 0, 0, 0);
        ((uint4*)(hnb + (size_t)N * 8))[1] = make_uint4(0, 0, 0, 0);
    }
}

// HETEROGENEOUS kernel (R14-proven: 45.7us vs 62 serial): partition + MFMA
// GEMM co-scheduled as block roles (4P:3L per group of 7; 7 coprime to the
// 8-XCD round-robin so roles mix on every XCD). LDS 53KB union. The GEMM
// writes UNSCALED bf16 h; the di scaling is applied at gather time in agg
// (R16: saves count_scale's 6.4MB hnb rescale round trip + one bf16 round).
__global__ __launch_bounds__(512)
void k_part_mm(const int* __restrict__ src, const int* __restrict__ dst,
               int* __restrict__ cursorC, int* __restrict__ packedC, int E,
               const float* __restrict__ x, const float* __restrict__ W1,
               unsigned* __restrict__ hnb, int N) {
    __shared__ alignas(16) char ldsraw[53312];
    int tid = threadIdx.x;
    int g7 = blockIdx.x / 7, r7 = blockIdx.x % 7;
    if (r7 < 4) {
        // ---------------- partition role ----------------
        int pb = g7 * 4 + r7;
        if (pb >= NB_P) return;
        int* csrB   = (int*)ldsraw;            // PCHUNK
        int* gposL  = csrB + PCHUNK;           // PCHUNK
        int* hist   = gposL + PCHUNK;          // 512
        int* gdelta = hist + 512;              // 512
        int* wsum   = gdelta + 512;            // 8
        hist[tid] = 0;
        int4 m1 = make_int4(-1, -1, -1, -1);
        for (int i = tid; i < PCHUNK / 4; i += PT) ((int4*)gposL)[i] = m1;
        __syncthreads();
        int base0 = pb * PCHUNK;
        int myp[EPT], myb[EPT];
#pragma unroll
        for (int k = 0; k < EPT; k++) {
            int e = base0 + k * PT + tid;
            if (e < E) {
                int d = dst[e];
                int b = d >> CSH;
                int pos = min(atomicAdd(&hist[b], 1), 126);
                myp[k] = (pos << 25) | ((d & 255) << 17) | src[e];
                myb[k] = b;
            } else myb[k] = -1;
        }
        __syncthreads();
        int v = hist[tid];
        int inc = block_scan_inc(v, wsum, tid, 8);
        int ex = inc - v;
        hist[tid] = ex;                       // lptr
        int gb = 0;
        if (tid < NC && v > 0) gb = atomicAdd(&cursorC[tid], v);
        gdelta[tid] = gb - ex;
        __syncthreads();
#pragma unroll
        for (int k = 0; k < EPT; k++) {
            int b = myb[k];
            if (b >= 0) {
                int a = myp[k];
                int slot = hist[b] + ((a >> 25) & 127);
                csrB[slot] = a & 0x1FFFFFF;   // (dl8<<17)|src
                int pg = gdelta[b] + slot;
                gposL[slot] = (pg < (b + 1) * CAPC) ? pg : -1;
            }
        }
        __syncthreads();
        int total = wsum[7];
        for (int i = tid; i < total; i += PT) {
            int gp = gposL[i];
            if (gp >= 0) packedC[gp] = csrB[i];  // coalesced runs
        }
    } else {
        // ---------------- MFMA GEMM role (unscaled h -> hnb) ----------------
        int lb = g7 * 3 + (r7 - 4);
        if (lb >= NC) return;
        float* stage = (float*)ldsraw;         // per-wave [32][17]
        int w = tid >> 6, l = tid & 63;
        int jj = l & 15, kg = l >> 4;          // B col (=W1 row) / k-group
        bf16x8 bfr[4];
#pragma unroll
        for (int ks = 0; ks < 4; ks++) {
            const float* wr = W1 + jj * FIN + ks * 32 + kg * 8;
            float4 wa = *(const float4*)wr;
            float4 wb = *(const float4*)(wr + 4);
            bf16x8 t;
            t[0] = (short)bf16rne(wa.x); t[1] = (short)bf16rne(wa.y);
            t[2] = (short)bf16rne(wa.z); t[3] = (short)bf16rne(wa.w);
            t[4] = (short)bf16rne(wb.x); t[5] = (short)bf16rne(wb.y);
            t[6] = (short)bf16rne(wb.z); t[7] = (short)bf16rne(wb.w);
            bfr[ks] = t;
        }
        float* lbuf = stage + w * 32 * 17;
#pragma unroll
        for (int q = 0; q < 2; q++) {          // 2 tiles of 16 nodes per wave
            int n0 = (lb << CSH) + w * 32 + q * 16;
            int row = min(n0 + jj, N - 1);     // clamp OOB x reads (tail bucket)
            const float* xr = x + (size_t)row * FIN + kg * 8;
            f32x4 acc = {0.f, 0.f, 0.f, 0.f};
#pragma unroll
            for (int ks = 0; ks < 4; ks++) {
                float4 xa = *(const float4*)(xr + ks * 32);
                float4 xb = *(const float4*)(xr + ks * 32 + 4);
                bf16x8 a;
                a[0] = (short)bf16rne(xa.x); a[1] = (short)bf16rne(xa.y);
                a[2] = (short)bf16rne(xa.z); a[3] = (short)bf16rne(xa.w);
                a[4] = (short)bf16rne(xb.x); a[5] = (short)bf16rne(xb.y);
                a[6] = (short)bf16rne(xb.z); a[7] = (short)bf16rne(xb.w);
                acc = __builtin_amdgcn_mfma_f32_16x16x32_bf16(a, bfr[ks], acc, 0, 0, 0);
            }
#pragma unroll
            for (int r = 0; r < 4; r++)        // D: node-in-tile kg*4+r, feat jj
                lbuf[(q * 16 + kg * 4 + r) * 17 + jj] = acc[r];
        }
        // epilogue (wave-private lbuf): pack UNSCALED bf16 h
        int pl = w * 32 + (l >> 1);            // local node 0..255
        int c = l & 1;                         // feature half
        int node = (lb << CSH) + pl;
        if (node < N) {
            const float* hb = lbuf + (l >> 1) * 17 + c * 8;
            uint4 o;
            o.x = bf16rne(hb[0]) | (bf16rne(hb[1]) << 16);
            o.y = bf16rne(hb[2]) | (bf16rne(hb[3]) << 16);
            o.z = bf16rne(hb[4]) | (bf16rne(hb[5]) << 16);
            o.w = bf16rne(hb[6]) | (bf16rne(hb[7]) << 16);
            ((uint4*)(hnb + ((size_t)node << 3)))[c] = o;
        }
    }
}

// histogram packedC (L2/L3-hot) -> degA (exact int, for agg's unbias) +
// dinv (for agg's per-edge source scaling). NO hnb touch (R16: hnb stays
// unscaled; di applied at gather).
__global__ __launch_bounds__(512)
void k_count(const int* __restrict__ packedC, const int* __restrict__ cursorC,
             int* __restrict__ degA, float* __restrict__ dinv, int N) {
    __shared__ int cnt[256];
    int tid = threadIdx.x;
    if (tid < 256) cnt[tid] = 0;
    __syncthreads();
    int bk = blockIdx.x;
    int st = bk * CAPC;
    int cntE = min(cursorC[bk] - st, CAPC);
    for (int i = tid; i < cntE; i += 512)
        atomicAdd(&cnt[(packedC[st + i] >> 17) & 255], 1);
    __syncthreads();
    if (tid < 256) {
        int node = (bk << CSH) + tid;
        if (node < N) {
            int deg = cnt[tid];
            degA[node] = deg;
            dinv[node] = rsqrtf((float)deg + 1.0f);
        }
    }
}

// SORT-FREE aggregation (packed-u64 biased Q16, proven ~16us). R16: hnb is
// UNSCALED; apply di_src at gather by folding it into the fixed-point scale
// (sc = dinv[s]*65536 — one L2-hot 4B broadcast load per edge-pair; agg is
// DS-bound so the extra VMEM overlaps). Bias bound unchanged: |h*di| range
// equals the old pre-scaled values -> 65 terms < 2^28, no field carry.
__global__ __launch_bounds__(1024)
void k_agg_fx(const int* __restrict__ packedC, const int* __restrict__ cursorC,
              const unsigned* __restrict__ hnb, const int* __restrict__ degA,
              const float* __restrict__ dinv, const float* __restrict__ b1,
              const float* __restrict__ W2, const float* __restrict__ b2,
              float* __restrict__ out, int N) {
    __shared__ unsigned long long accJ[256 * 9];   // 18.4 KB
    int tid = threadIdx.x;
    for (int i = tid; i < 256 * 9; i += 1024) accJ[i] = 0ull;
    __syncthreads();
    int bk = blockIdx.x;
    int st = bk * CAPC;
    int cntE = min(cursorC[bk] - st, CAPC);
    int c = tid & 1;
    int co = c << 2;   // uint offset into 32B hnb row
    int c4 = c << 2;   // u64 slot offset (4 u64 = 8 features per lane)
    int c8 = c << 3;
#define PK(u, sc)                                                               \
    ((unsigned long long)(unsigned)((int)(__uint_as_float((u) << 16) * (sc)) + FXB) | \
     ((unsigned long long)(unsigned)((int)(__uint_as_float((u) & 0xFFFF0000u) * (sc)) + FXB) << 32))
    for (int i = (tid >> 1); i < cntE; i += 512) {
        int pv = packedC[st + i];
        int dl8 = (pv >> 17) & 255;
        int s = pv & 0x1FFFF;
        uint4 w = *(const uint4*)(hnb + ((size_t)s << 3) + co);
        float sc = dinv[s] * 65536.0f;     // di_src folded into Q16 scale
        unsigned long long* a = accJ + dl8 * 9 + c4;
        atomicAdd(a + 0, PK(w.x, sc));
        atomicAdd(a + 1, PK(w.y, sc));
        atomicAdd(a + 2, PK(w.z, sc));
        atomicAdd(a + 3, PK(w.w, sc));
    }
#undef PK
    __syncthreads();
    if (tid < 512) {
        int p = tid >> 1;                  // local node
        int node = (bk << CSH) + p;
        if (node < N) {
            const unsigned long long* a = accJ + p * 9 + c4;
            int deg = degA[node];
            int ub = deg << 20;            // total bias per field
            float din = dinv[node];
            uint4 ws = *(const uint4*)(hnb + ((size_t)node << 3) + co);  // self (unscaled)
            unsigned long long q0 = a[0], q1 = a[1], q2 = a[2], q3 = a[3];
            float a0 = (float)((int)(unsigned)(q0 & 0xFFFFFFFFull) - ub) * IS16 + __uint_as_float(ws.x << 16) * din;
            float a1 = (float)((int)(unsigned)(q0 >> 32) - ub) * IS16 + __uint_as_float(ws.x & 0xFFFF0000u) * din;
            float a2 = (float)((int)(unsigned)(q1 & 0xFFFFFFFFull) - ub) * IS16 + __uint_as_float(ws.y << 16) * din;
            float a3 = (float)((int)(unsigned)(q1 >> 32) - ub) * IS16 + __uint_as_float(ws.y & 0xFFFF0000u) * din;
            float a4 = (float)((int)(unsigned)(q2 & 0xFFFFFFFFull) - ub) * IS16 + __uint_as_float(ws.z << 16) * din;
            float a5 = (float)((int)(unsigned)(q2 >> 32) - ub) * IS16 + __uint_as_float(ws.z & 0xFFFF0000u) * din;
            float a6 = (float)((int)(unsigned)(q3 & 0xFFFFFFFFull) - ub) * IS16 + __uint_as_float(ws.w << 16) * din;
            float a7 = (float)((int)(unsigned)(q3 >> 32) - ub) * IS16 + __uint_as_float(ws.w & 0xFFFF0000u) * din;
            float t0 = fmaxf(a0 * din + b1[c8 + 0], 0.0f);
            float t1 = fmaxf(a1 * din + b1[c8 + 1], 0.0f);
            float t2 = fmaxf(a2 * din + b1[c8 + 2], 0.0f);
            float t3 = fmaxf(a3 * din + b1[c8 + 3], 0.0f);
            float t4 = fmaxf(a4 * din + b1[c8 + 4], 0.0f);
            float t5 = fmaxf(a5 * din + b1[c8 + 5], 0.0f);
            float t6 = fmaxf(a6 * din + b1[c8 + 6], 0.0f);
            float t7 = fmaxf(a7 * din + b1[c8 + 7], 0.0f);
            float o0 = t0 * W2[c8 + 0] + t1 * W2[c8 + 1] + t2 * W2[c8 + 2] + t3 * W2[c8 + 3] +
                       t4 * W2[c8 + 4] + t5 * W2[c8 + 5] + t6 * W2[c8 + 6] + t7 * W2[c8 + 7];
            float o1 = t0 * W2[FHID + c8 + 0] + t1 * W2[FHID + c8 + 1] +
                       t2 * W2[FHID + c8 + 2] + t3 * W2[FHID + c8 + 3] +
                       t4 * W2[FHID + c8 + 4] + t5 * W2[FHID + c8 + 5] +
                       t6 * W2[FHID + c8 + 6] + t7 * W2[FHID + c8 + 7];
            o0 += __shfl_down(o0, 1, 2);
            o1 += __shfl_down(o1, 1, 2);
            if (c == 0) ((float2*)out)[node] = make_float2(o0 + b2[0], o1 + b2[1]);
        }
    }
}

// ---------------- launch ----------------

extern "C" void kernel_launch(void* const* d_in, const int* in_sizes, int n_in,
                              void* d_out, int out_size, void* d_ws, size_t ws_size,
                              hipStream_t stream) {
    const float* x  = (const float*)d_in[0];
    const int* ei   = (const int*)d_in[1];
    const float* W1 = (const float*)d_in[2];
    const float* b1 = (const float*)d_in[3];
    const float* W2 = (const float*)d_in[4];
    const float* b2 = (const float*)d_in[5];
    float* out = (float*)d_out;

    const int N = in_sizes[0] / FIN;   // 100000
    const int E = in_sizes[1] / 2;     // 3200000
    const int* src = ei;
    const int* dst = ei + E;

    // heterogeneous grid: groups of 7 = 4 partition + 3 lin1 roles (R14)
    const int gH = 7 * ((NB_P + 3) / 4);       // 917 blocks (excess early-exits)

    // workspace layout (all component sizes %4 ints -> 16B alignment preserved)
    unsigned* hnb  = (unsigned*)d_ws;                       // (N+1)*8 uints
    int* degA      = (int*)(hnb + (size_t)(N + 1) * 8);     // N ints
    float* dinv    = (float*)(degA + N);                    // N floats
    int* cursorC   = (int*)(dinv + N);                      // 512
    int* packedC   = cursorC + 512;                         // NC*CAPC

    k_init<<<1, 512, 0, stream>>>(cursorC, hnb, N);
    k_part_mm<<<gH, PT, 0, stream>>>(src, dst, cursorC, packedC, E, x, W1, hnb, N);
    k_count<<<NC, 512, 0, stream>>>(packedC, cursorC, degA, dinv, N);
    k_agg_fx<<<NC, 1024, 0, stream>>>(packedC, cursorC, hnb, degA, dinv, b1, W2, b2, out, N);
}

// Round 17
// 158.858 us; speedup vs baseline: 1.1047x; 1.1047x over previous
//
#include <hip/hip_runtime.h>

#define FIN 128
#define FHID 16
#define NC 391           // coarse buckets (256 nodes each)
#define CSH 8
#define CAPC 9728        // per-bucket capacity (mean 8184; %4==0; mean+17sigma)
#define PCHUNK 6144      // R14-proven (3072 regressed: fixed costs doubled)
#define PT 512
#define EPT 12           // PCHUNK/PT
#define NB_P 521         // partition blocks
#define FXB (1 << 20)    // per-term bias: term_fx = (int)(w*2^16) + FXB >= 0
#define IS16 (1.0f / 65536.0f)

typedef __attribute__((ext_vector_type(8))) short bf16x8;
typedef __attribute__((ext_vector_type(4))) float f32x4;

__device__ __forceinline__ unsigned bf16rne(float f) {
    unsigned u = __float_as_uint(f);
    return (u + 0x7FFFu + ((u >> 16) & 1u)) >> 16;
}

// block-wide inclusive scan via wave shfl; wsum = LDS[8]; 2 barriers.
__device__ __forceinline__ int block_scan_inc(int v, int* wsum, int tid, int nw) {
#pragma unroll
    for (int off = 1; off < 64; off <<= 1) {
        int t = __shfl_up(v, off, 64);
        if ((tid & 63) >= off) v += t;
    }
    int wid = tid >> 6;
    if ((tid & 63) == 63) wsum[wid] = v;
    __syncthreads();
    if (tid < nw) {
        int s = wsum[tid];
#pragma unroll
        for (int off = 1; off < 8; off <<= 1) {
            int t = __shfl_up(s, off, 64);
            if (tid >= off) s += t;
        }
        wsum[tid] = s;
    }
    __syncthreads();
    if (wid > 0) v += wsum[wid - 1];
    return v;
}

// ---------------- kernels ----------------

__global__ void k_init(int* __restrict__ cursorC, unsigned* __restrict__ hnb, int N) {
    int b = threadIdx.x;
    if (b < NC) cursorC[b] = b * CAPC;
    if (b == 0) {                          // zero sentinel row N of hnb
        ((uint4*)(hnb + (size_t)N * 8))[0] = make_uint4(0, 0, 0, 0);
        ((uint4*)(hnb + (size_t)N * 8))[1] = make_uint4(0, 0, 0, 0);
    }
}

// HETEROGENEOUS kernel (R14-proven best: 45.7us vs 62 serial): partition +
// MFMA GEMM co-scheduled as block roles (4P:3L per group of 7; 7 coprime to
// the 8-XCD round-robin so roles mix on every XCD). LDS 53KB union. GEMM
// writes UNSCALED bf16 h; count_scale applies di afterwards (R16 lesson:
// gather-time di costs +23us — keep the streaming rescale).
__global__ __launch_bounds__(512)
void k_part_mm(const int* __restrict__ src, const int* __restrict__ dst,
               int* __restrict__ cursorC, int* __restrict__ packedC, int E,
               const float* __restrict__ x, const float* __restrict__ W1,
               unsigned* __restrict__ hnb, int N) {
    __shared__ alignas(16) char ldsraw[53312];
    int tid = threadIdx.x;
    int g7 = blockIdx.x / 7, r7 = blockIdx.x % 7;
    if (r7 < 4) {
        // ---------------- partition role ----------------
        int pb = g7 * 4 + r7;
        if (pb >= NB_P) return;
        int* csrB   = (int*)ldsraw;            // PCHUNK
        int* gposL  = csrB + PCHUNK;           // PCHUNK
        int* hist   = gposL + PCHUNK;          // 512
        int* gdelta = hist + 512;              // 512
        int* wsum   = gdelta + 512;            // 8
        hist[tid] = 0;
        int4 m1 = make_int4(-1, -1, -1, -1);
        for (int i = tid; i < PCHUNK / 4; i += PT) ((int4*)gposL)[i] = m1;
        __syncthreads();
        int base0 = pb * PCHUNK;
        int myp[EPT], myb[EPT];
#pragma unroll
        for (int k = 0; k < EPT; k++) {
            int e = base0 + k * PT + tid;
            if (e < E) {
                int d = dst[e];
                int b = d >> CSH;
                int pos = min(atomicAdd(&hist[b], 1), 126);
                myp[k] = (pos << 25) | ((d & 255) << 17) | src[e];
                myb[k] = b;
            } else myb[k] = -1;
        }
        __syncthreads();
        int v = hist[tid];
        int inc = block_scan_inc(v, wsum, tid, 8);
        int ex = inc - v;
        hist[tid] = ex;                       // lptr
        int gb = 0;
        if (tid < NC && v > 0) gb = atomicAdd(&cursorC[tid], v);
        gdelta[tid] = gb - ex;
        __syncthreads();
#pragma unroll
        for (int k = 0; k < EPT; k++) {
            int b = myb[k];
            if (b >= 0) {
                int a = myp[k];
                int slot = hist[b] + ((a >> 25) & 127);
                csrB[slot] = a & 0x1FFFFFF;   // (dl8<<17)|src
                int pg = gdelta[b] + slot;
                gposL[slot] = (pg < (b + 1) * CAPC) ? pg : -1;
            }
        }
        __syncthreads();
        int total = wsum[7];
        for (int i = tid; i < total; i += PT) {
            int gp = gposL[i];
            if (gp >= 0) packedC[gp] = csrB[i];  // coalesced runs
        }
    } else {
        // ---------------- MFMA GEMM role (unscaled h -> hnb) ----------------
        int lb = g7 * 3 + (r7 - 4);
        if (lb >= NC) return;
        float* stage = (float*)ldsraw;         // per-wave [32][17]
        int w = tid >> 6, l = tid & 63;
        int jj = l & 15, kg = l >> 4;          // B col (=W1 row) / k-group
        bf16x8 bfr[4];
#pragma unroll
        for (int ks = 0; ks < 4; ks++) {
            const float* wr = W1 + jj * FIN + ks * 32 + kg * 8;
            float4 wa = *(const float4*)wr;
            float4 wb = *(const float4*)(wr + 4);
            bf16x8 t;
            t[0] = (short)bf16rne(wa.x); t[1] = (short)bf16rne(wa.y);
            t[2] = (short)bf16rne(wa.z); t[3] = (short)bf16rne(wa.w);
            t[4] = (short)bf16rne(wb.x); t[5] = (short)bf16rne(wb.y);
            t[6] = (short)bf16rne(wb.z); t[7] = (short)bf16rne(wb.w);
            bfr[ks] = t;
        }
        float* lbuf = stage + w * 32 * 17;
#pragma unroll
        for (int q = 0; q < 2; q++) {          // 2 tiles of 16 nodes per wave
            int n0 = (lb << CSH) + w * 32 + q * 16;
            int row = min(n0 + jj, N - 1);     // clamp OOB x reads (tail bucket)
            const float* xr = x + (size_t)row * FIN + kg * 8;
            f32x4 acc = {0.f, 0.f, 0.f, 0.f};
#pragma unroll
            for (int ks = 0; ks < 4; ks++) {
                float4 xa = *(const float4*)(xr + ks * 32);
                float4 xb = *(const float4*)(xr + ks * 32 + 4);
                bf16x8 a;
                a[0] = (short)bf16rne(xa.x); a[1] = (short)bf16rne(xa.y);
                a[2] = (short)bf16rne(xa.z); a[3] = (short)bf16rne(xa.w);
                a[4] = (short)bf16rne(xb.x); a[5] = (short)bf16rne(xb.y);
                a[6] = (short)bf16rne(xb.z); a[7] = (short)bf16rne(xb.w);
                acc = __builtin_amdgcn_mfma_f32_16x16x32_bf16(a, bfr[ks], acc, 0, 0, 0);
            }
#pragma unroll
            for (int r = 0; r < 4; r++)        // D: node-in-tile kg*4+r, feat jj
                lbuf[(q * 16 + kg * 4 + r) * 17 + jj] = acc[r];
        }
        // epilogue (wave-private lbuf): pack UNSCALED bf16 h
        int pl = w * 32 + (l >> 1);            // local node 0..255
        int c = l & 1;                         // feature half
        int node = (lb << CSH) + pl;
        if (node < N) {
            const float* hb = lbuf + (l >> 1) * 17 + c * 8;
            uint4 o;
            o.x = bf16rne(hb[0]) | (bf16rne(hb[1]) << 16);
            o.y = bf16rne(hb[2]) | (bf16rne(hb[3]) << 16);
            o.z = bf16rne(hb[4]) | (bf16rne(hb[5]) << 16);
            o.w = bf16rne(hb[6]) | (bf16rne(hb[7]) << 16);
            ((uint4*)(hnb + ((size_t)node << 3)))[c] = o;
        }
    }
}

// histogram packedC (L2/L3-hot) -> deg -> degA; rescale hnb rows in place by
// di = rsqrtf(deg+1). 512 threads: lane-pair per node (c = 16B half-row).
// Streaming, coalesced — 7us (R16 proved the gather-time alternative is +23).
__global__ __launch_bounds__(512)
void k_count_scale(const int* __restrict__ packedC, const int* __restrict__ cursorC,
                   int* __restrict__ degA, unsigned* __restrict__ hnb, int N) {
    __shared__ int cnt[256];
    int tid = threadIdx.x;
    if (tid < 256) cnt[tid] = 0;
    __syncthreads();
    int bk = blockIdx.x;
    int st = bk * CAPC;
    int cntE = min(cursorC[bk] - st, CAPC);
    for (int i = tid; i < cntE; i += 512)
        atomicAdd(&cnt[(packedC[st + i] >> 17) & 255], 1);
    __syncthreads();
    int p = tid >> 1;
    int c = tid & 1;
    int node = (bk << CSH) + p;
    if (node < N) {
        int deg = cnt[p];
        if (c == 0) degA[node] = deg;
        float di = rsqrtf((float)deg + 1.0f);
        uint4 v = ((uint4*)(hnb + ((size_t)node << 3)))[c];
        uint4 o;
        o.x = bf16rne(__uint_as_float(v.x << 16) * di) |
              (bf16rne(__uint_as_float(v.x & 0xFFFF0000u) * di) << 16);
        o.y = bf16rne(__uint_as_float(v.y << 16) * di) |
              (bf16rne(__uint_as_float(v.y & 0xFFFF0000u) * di) << 16);
        o.z = bf16rne(__uint_as_float(v.z << 16) * di) |
              (bf16rne(__uint_as_float(v.z & 0xFFFF0000u) * di) << 16);
        o.w = bf16rne(__uint_as_float(v.w << 16) * di) |
              (bf16rne(__uint_as_float(v.w & 0xFFFF0000u) * di) << 16);
        ((uint4*)(hnb + ((size_t)node << 3)))[c] = o;
    }
}

// SORT-FREE aggregation (packed-u64 biased Q16; proven ~20us, near DS floor).
// Field = sum((int)(w*2^16) + 2^20); 65 terms < 2^28 -> no field carry.
__global__ __launch_bounds__(1024)
void k_agg_fx(const int* __restrict__ packedC, const int* __restrict__ cursorC,
              const unsigned* __restrict__ hnb, const int* __restrict__ degA,
              const float* __restrict__ b1, const float* __restrict__ W2,
              const float* __restrict__ b2, float* __restrict__ out, int N) {
    __shared__ unsigned long long accJ[256 * 9];   // 18.4 KB
    int tid = threadIdx.x;
    for (int i = tid; i < 256 * 9; i += 1024) accJ[i] = 0ull;
    __syncthreads();
    int bk = blockIdx.x;
    int st = bk * CAPC;
    int cntE = min(cursorC[bk] - st, CAPC);
    int c = tid & 1;
    int co = c << 2;   // uint offset into 32B hnb row
    int c4 = c << 2;   // u64 slot offset (4 u64 = 8 features per lane)
    int c8 = c << 3;
#define PK(u)                                                                   \
    ((unsigned long long)(unsigned)((int)(__uint_as_float((u) << 16) * 65536.0f) + FXB) | \
     ((unsigned long long)(unsigned)((int)(__uint_as_float((u) & 0xFFFF0000u) * 65536.0f) + FXB) << 32))
    for (int i = (tid >> 1); i < cntE; i += 512) {
        int pv = packedC[st + i];
        int dl8 = (pv >> 17) & 255;
        int s = pv & 0x1FFFF;
        uint4 w = *(const uint4*)(hnb + ((size_t)s << 3) + co);
        unsigned long long* a = accJ + dl8 * 9 + c4;
        atomicAdd(a + 0, PK(w.x));
        atomicAdd(a + 1, PK(w.y));
        atomicAdd(a + 2, PK(w.z));
        atomicAdd(a + 3, PK(w.w));
    }
#undef PK
    __syncthreads();
    if (tid < 512) {
        int p = tid >> 1;                  // local node
        int node = (bk << CSH) + p;
        if (node < N) {
            const unsigned long long* a = accJ + p * 9 + c4;
            int deg = degA[node];
            int ub = deg << 20;            // total bias per field
            uint4 ws = *(const uint4*)(hnb + ((size_t)node << 3) + co);  // self-loop
            unsigned long long q0 = a[0], q1 = a[1], q2 = a[2], q3 = a[3];
            float a0 = (float)((int)(unsigned)(q0 & 0xFFFFFFFFull) - ub) * IS16 + __uint_as_float(ws.x << 16);
            float a1 = (float)((int)(unsigned)(q0 >> 32) - ub) * IS16 + __uint_as_float(ws.x & 0xFFFF0000u);
            float a2 = (float)((int)(unsigned)(q1 & 0xFFFFFFFFull) - ub) * IS16 + __uint_as_float(ws.y << 16);
            float a3 = (float)((int)(unsigned)(q1 >> 32) - ub) * IS16 + __uint_as_float(ws.y & 0xFFFF0000u);
            float a4 = (float)((int)(unsigned)(q2 & 0xFFFFFFFFull) - ub) * IS16 + __uint_as_float(ws.z << 16);
            float a5 = (float)((int)(unsigned)(q2 >> 32) - ub) * IS16 + __uint_as_float(ws.z & 0xFFFF0000u);
            float a6 = (float)((int)(unsigned)(q3 & 0xFFFFFFFFull) - ub) * IS16 + __uint_as_float(ws.w << 16);
            float a7 = (float)((int)(unsigned)(q3 >> 32) - ub) * IS16 + __uint_as_float(ws.w & 0xFFFF0000u);
            float di = rsqrtf((float)deg + 1.0f);  // matches count_scale
            float t0 = fmaxf(a0 * di + b1[c8 + 0], 0.0f);
            float t1 = fmaxf(a1 * di + b1[c8 + 1], 0.0f);
            float t2 = fmaxf(a2 * di + b1[c8 + 2], 0.0f);
            float t3 = fmaxf(a3 * di + b1[c8 + 3], 0.0f);
            float t4 = fmaxf(a4 * di + b1[c8 + 4], 0.0f);
            float t5 = fmaxf(a5 * di + b1[c8 + 5], 0.0f);
            float t6 = fmaxf(a6 * di + b1[c8 + 6], 0.0f);
            float t7 = fmaxf(a7 * di + b1[c8 + 7], 0.0f);
            float o0 = t0 * W2[c8 + 0] + t1 * W2[c8 + 1] + t2 * W2[c8 + 2] + t3 * W2[c8 + 3] +
                       t4 * W2[c8 + 4] + t5 * W2[c8 + 5] + t6 * W2[c8 + 6] + t7 * W2[c8 + 7];
            float o1 = t0 * W2[FHID + c8 + 0] + t1 * W2[FHID + c8 + 1] +
                       t2 * W2[FHID + c8 + 2] + t3 * W2[FHID + c8 + 3] +
                       t4 * W2[FHID + c8 + 4] + t5 * W2[FHID + c8 + 5] +
                       t6 * W2[FHID + c8 + 6] + t7 * W2[FHID + c8 + 7];
            o0 += __shfl_down(o0, 1, 2);
            o1 += __shfl_down(o1, 1, 2);
            if (c == 0) ((float2*)out)[node] = make_float2(o0 + b2[0], o1 + b2[1]);
        }
    }
}

// ---------------- launch ----------------

extern "C" void kernel_launch(void* const* d_in, const int* in_sizes, int n_in,
                              void* d_out, int out_size, void* d_ws, size_t ws_size,
                              hipStream_t stream) {
    const float* x  = (const float*)d_in[0];
    const int* ei   = (const int*)d_in[1];
    const float* W1 = (const float*)d_in[2];
    const float* b1 = (const float*)d_in[3];
    const float* W2 = (const float*)d_in[4];
    const float* b2 = (const float*)d_in[5];
    float* out = (float*)d_out;

    const int N = in_sizes[0] / FIN;   // 100000
    const int E = in_sizes[1] / 2;     // 3200000
    const int* src = ei;
    const int* dst = ei + E;

    // heterogeneous grid: groups of 7 = 4 partition + 3 lin1 roles
    const int gH = 7 * ((NB_P + 3) / 4);       // 917 blocks (excess early-exits)

    // workspace layout (all component sizes %4 ints -> 16B alignment preserved)
    unsigned* hnb  = (unsigned*)d_ws;                       // (N+1)*8 uints
    int* degA      = (int*)(hnb + (size_t)(N + 1) * 8);     // N ints
    int* cursorC   = degA + N;                              // 512
    int* packedC   = cursorC + 512;                         // NC*CAPC

    k_init<<<1, 512, 0, stream>>>(cursorC, hnb, N);
    k_part_mm<<<gH, PT, 0, stream>>>(src, dst, cursorC, packedC, E, x, W1, hnb, N);
    k_count_scale<<<NC, 512, 0, stream>>>(packedC, cursorC, degA, hnb, N);
    k_agg_fx<<<NC, 1024, 0, stream>>>(packedC, cursorC, hnb, degA, b1, W2, b2, out, N);
}